// Round 2
// baseline (683.364 us; speedup 1.0000x reference)
//
#include <hip/hip_runtime.h>
#include <hip/hip_bf16.h>

#define H2 16
#define HKV 8
#define DHEAD 128
#define HID 1024
#define NQ 2048

typedef unsigned short u16;
typedef __bf16 bf16x8 __attribute__((ext_vector_type(8)));
typedef float f32x4 __attribute__((ext_vector_type(4)));

__device__ __forceinline__ u16 f2bf(float x) {
    unsigned int u = __float_as_uint(x);
    unsigned int r = (u + 0x7fffu + ((u >> 16) & 1u)) >> 16;
    return (u16)r;
}

__device__ __forceinline__ bf16x8 ld_frag(const u16* p) {
    bf16x8 r;
    reinterpret_cast<uint2*>(&r)[0] = *reinterpret_cast<const uint2*>(p);
    reinterpret_cast<uint2*>(&r)[1] = *reinterpret_cast<const uint2*>(p + 4);
    return r;
}

// ---------------- cast x fp32 -> bf16 ----------------
__global__ __launch_bounds__(256) void cast_f32_bf16(const float* __restrict__ in,
                                                     u16* __restrict__ out, int n4) {
    int i = blockIdx.x * 256 + threadIdx.x;
    if (i < n4) {
        float4 v = reinterpret_cast<const float4*>(in)[i];
        ushort4 o;
        o.x = f2bf(v.x); o.y = f2bf(v.y); o.z = f2bf(v.z); o.w = f2bf(v.w);
        reinterpret_cast<ushort4*>(out)[i] = o;
    }
}

// ---------------- transpose-cast W [K][N] fp32 -> [N][K] bf16 ----------------
__global__ __launch_bounds__(256) void transpose_cast(const float* __restrict__ in,
                                                      u16* __restrict__ out, int K, int N) {
    __shared__ u16 t[32][34];
    int k0 = blockIdx.x * 32, n0 = blockIdx.y * 32;
    for (int c = threadIdx.x; c < 1024; c += 256) {
        int k = c >> 5, n = c & 31;
        t[k][n] = f2bf(in[(size_t)(k0 + k) * N + n0 + n]);
    }
    __syncthreads();
    for (int c = threadIdx.x; c < 1024; c += 256) {
        int n = c >> 5, k = c & 31;
        out[(size_t)(n0 + n) * K + k0 + k] = t[k][n];
    }
}

// ---------------- GEMM: C[M,N] fp32 = A[M,K]bf16 @ Bt[N,K]bf16^T ----------------
__global__ __launch_bounds__(256) void gemm_bf16(const u16* __restrict__ A,
                                                 const u16* __restrict__ Bt,
                                                 float* __restrict__ C,
                                                 int M, int N, int K) {
    __shared__ u16 As[128][40];
    __shared__ u16 Bs[128][40];
    int tid = threadIdx.x;
    int lane = tid & 63, wave = tid >> 6;
    int quad = lane >> 4, l15 = lane & 15;
    int wr = wave >> 1, wc = wave & 1;
    int m0 = blockIdx.y * 128, n0 = blockIdx.x * 128;

    f32x4 zero = {0.f, 0.f, 0.f, 0.f};
    f32x4 acc[4][4];
    for (int i = 0; i < 4; i++)
        for (int j = 0; j < 4; j++) acc[i][j] = zero;

    int srow = tid >> 1, shalf = tid & 1;
    const u16* ga = A + (size_t)(m0 + srow) * K + shalf * 16;
    const u16* gb = Bt + (size_t)(n0 + srow) * K + shalf * 16;

    for (int k0 = 0; k0 < K; k0 += 32) {
        __syncthreads();
        {
            const uint2* pa = reinterpret_cast<const uint2*>(ga + k0);
            const uint2* pb = reinterpret_cast<const uint2*>(gb + k0);
            uint2* da = reinterpret_cast<uint2*>(&As[srow][shalf * 16]);
            uint2* db = reinterpret_cast<uint2*>(&Bs[srow][shalf * 16]);
            da[0] = pa[0]; da[1] = pa[1]; da[2] = pa[2]; da[3] = pa[3];
            db[0] = pb[0]; db[1] = pb[1]; db[2] = pb[2]; db[3] = pb[3];
        }
        __syncthreads();
        bf16x8 a[4], b[4];
        for (int i = 0; i < 4; i++) a[i] = ld_frag(&As[64 * wr + 16 * i + l15][quad * 8]);
        for (int j = 0; j < 4; j++) b[j] = ld_frag(&Bs[64 * wc + 16 * j + l15][quad * 8]);
        for (int i = 0; i < 4; i++)
            for (int j = 0; j < 4; j++)
                acc[i][j] = __builtin_amdgcn_mfma_f32_16x16x32_bf16(a[i], b[j], acc[i][j], 0, 0, 0);
    }
    for (int i = 0; i < 4; i++) {
        int rowb = m0 + 64 * wr + 16 * i + quad * 4;
        for (int j = 0; j < 4; j++) {
            int col = n0 + 64 * wc + 16 * j + l15;
            for (int r = 0; r < 4; r++)
                C[(size_t)(rowb + r) * N + col] = acc[i][j][r];
        }
    }
}

// ---------------- fused RMSNorm + RoPE, fp32 in -> bf16 head-major out ----------------
__global__ __launch_bounds__(256) void norm_rope(const float* __restrict__ raw,
                                                 const float* __restrict__ cosp,
                                                 const float* __restrict__ sinp,
                                                 const float* __restrict__ w,
                                                 u16* __restrict__ out,
                                                 int T, int nh, float outscale) {
    int wave = threadIdx.x >> 6, lane = threadIdx.x & 63;
    int wid = blockIdx.x * 4 + wave;
    int t = wid / nh, h = wid % nh;
    if (t >= T) return;
    const float* r = raw + (size_t)t * nh * 128 + h * 128;
    float v1 = r[lane], v2 = r[lane + 64];
    float ss = v1 * v1 + v2 * v2;
    for (int off = 1; off < 64; off <<= 1) ss += __shfl_xor(ss, off);
    float inv = rsqrtf(ss * (1.f / 128.f) + 1e-6f);
    float n1 = v1 * inv * w[lane], n2 = v2 * inv * w[lane + 64];
    float c = cosp[(size_t)t * 64 + lane], s = sinp[(size_t)t * 64 + lane];
    float o1 = (n1 * c - n2 * s) * outscale;
    float o2 = (n1 * s + n2 * c) * outscale;
    u16* op = out + ((size_t)h * T + t) * 128;
    op[lane] = f2bf(o1);
    op[lane + 64] = f2bf(o2);
}

// ---------------- V: [T][1024] fp32 -> [h][d][T] bf16 ----------------
__global__ __launch_bounds__(256) void v_transpose(const float* __restrict__ vraw,
                                                   u16* __restrict__ Vbt, int T) {
    __shared__ u16 tt[128][72];
    int h = blockIdx.y, t0 = blockIdx.x * 64;
    for (int c = threadIdx.x; c < 8192; c += 256) {
        int r = c >> 7, d = c & 127;
        tt[d][r] = f2bf(vraw[(size_t)(t0 + r) * HID + h * 128 + d]);
    }
    __syncthreads();
    for (int c = threadIdx.x; c < 8192; c += 256) {
        int d = c >> 6, r = c & 63;
        Vbt[((size_t)h * 128 + d) * T + t0 + r] = tt[d][r];
    }
}

// ---------------- causal MFMA flash attention ----------------
__global__ __launch_bounds__(256) void flash_attn(const u16* __restrict__ Qb,
                                                  const u16* __restrict__ Kb,
                                                  const u16* __restrict__ Vbt,
                                                  u16* __restrict__ attn, int T) {
    __shared__ u16 Ks[64][136];
    __shared__ u16 Vt[128][72];
    __shared__ u16 Ps[64][72];
    int tid = threadIdx.x;
    int lane = tid & 63, wave = tid >> 6;
    int quad = lane >> 4, l15 = lane & 15;
    int h = blockIdx.y;
    int qt = (int)gridDim.x - 1 - (int)blockIdx.x;  // heavy blocks first
    int q0 = qt * 64;
    int kvh = h >> 1;

    bf16x8 qf[4];
    {
        const u16* qp = Qb + ((size_t)h * T + q0 + 16 * wave + l15) * 128 + quad * 8;
        for (int kk = 0; kk < 4; kk++) qf[kk] = ld_frag(qp + kk * 32);
    }

    f32x4 zero = {0.f, 0.f, 0.f, 0.f};
    float m_i[4], l_i[4];
    f32x4 o[8];
    for (int r = 0; r < 4; r++) { m_i[r] = -3.0e38f; l_i[r] = 0.f; }
    for (int dt = 0; dt < 8; dt++) o[dt] = zero;

    const u16* kbase = Kb + (size_t)kvh * T * 128;
    const u16* vbase = Vbt + (size_t)kvh * 128 * T;

    for (int s0 = 0; s0 <= q0; s0 += 64) {
        __syncthreads();
        for (int c = tid; c < 1024; c += 256) {
            int key = c >> 4, seg = c & 15;  // FIXED: full 64x128 tile (was c<512, half-row)
            *reinterpret_cast<uint4*>(&Ks[key][seg * 8]) =
                *reinterpret_cast<const uint4*>(kbase + (size_t)(s0 + key) * 128 + seg * 8);
        }
        for (int c = tid; c < 1024; c += 256) {
            int d = c >> 3, seg = c & 7;
            *reinterpret_cast<uint4*>(&Vt[d][seg * 8]) =
                *reinterpret_cast<const uint4*>(vbase + (size_t)d * T + s0 + seg * 8);
        }
        __syncthreads();

        f32x4 sc[4];
        for (int jt = 0; jt < 4; jt++) sc[jt] = zero;
        for (int kk = 0; kk < 4; kk++)
            for (int jt = 0; jt < 4; jt++) {
                bf16x8 b = ld_frag(&Ks[jt * 16 + l15][kk * 32 + quad * 8]);
                sc[jt] = __builtin_amdgcn_mfma_f32_16x16x32_bf16(qf[kk], b, sc[jt], 0, 0, 0);
            }

        if (s0 == q0) {  // diagonal tile: mask col > row (q0 == s0 cancels)
            for (int jt = 0; jt < 4; jt++) {
                int col = jt * 16 + l15;
                for (int r = 0; r < 4; r++) {
                    int row = 16 * wave + quad * 4 + r;
                    if (col > row) sc[jt][r] = -1e30f;
                }
            }
        }

        float alpha[4];
        for (int r = 0; r < 4; r++) {
            float mt = fmaxf(fmaxf(sc[0][r], sc[1][r]), fmaxf(sc[2][r], sc[3][r]));
            for (int off = 1; off < 16; off <<= 1) mt = fmaxf(mt, __shfl_xor(mt, off));
            float mnew = fmaxf(m_i[r], mt);
            alpha[r] = __expf(m_i[r] - mnew);
            m_i[r] = mnew;
            float rs = 0.f;
            for (int jt = 0; jt < 4; jt++) {
                float p = __expf(sc[jt][r] - mnew);
                sc[jt][r] = p;
                rs += p;
            }
            for (int off = 1; off < 16; off <<= 1) rs += __shfl_xor(rs, off);
            l_i[r] = l_i[r] * alpha[r] + rs;
        }

        for (int jt = 0; jt < 4; jt++)
            for (int r = 0; r < 4; r++)
                Ps[16 * wave + quad * 4 + r][jt * 16 + l15] = f2bf(sc[jt][r]);
        __syncthreads();  // P visibility (per-wave rows; conservative)

        for (int dt = 0; dt < 8; dt++)
            for (int r = 0; r < 4; r++) o[dt][r] *= alpha[r];

        for (int kk2 = 0; kk2 < 2; kk2++) {
            bf16x8 pa = ld_frag(&Ps[16 * wave + l15][kk2 * 32 + quad * 8]);
            for (int dt = 0; dt < 8; dt++) {
                bf16x8 vb = ld_frag(&Vt[dt * 16 + l15][kk2 * 32 + quad * 8]);
                o[dt] = __builtin_amdgcn_mfma_f32_16x16x32_bf16(pa, vb, o[dt], 0, 0, 0);
            }
        }
    }

    float inv[4];
    for (int r = 0; r < 4; r++) inv[r] = 1.f / l_i[r];
    for (int dt = 0; dt < 8; dt++)
        for (int r = 0; r < 4; r++) {
            int row = q0 + 16 * wave + quad * 4 + r;
            attn[(size_t)row * NQ + h * DHEAD + dt * 16 + l15] = f2bf(o[dt][r] * inv[r]);
        }
}

extern "C" void kernel_launch(void* const* d_in, const int* in_sizes, int n_in,
                              void* d_out, int out_size, void* d_ws, size_t ws_size,
                              hipStream_t stream) {
    const float* x    = (const float*)d_in[0];
    const float* cosp = (const float*)d_in[1];
    const float* sinp = (const float*)d_in[2];
    const float* Wq   = (const float*)d_in[3];
    const float* Wk   = (const float*)d_in[4];
    const float* Wv   = (const float*)d_in[5];
    const float* Wo   = (const float*)d_in[6];
    const float* qnw  = (const float*)d_in[7];
    const float* knw  = (const float*)d_in[8];
    float* out = (float*)d_out;
    const int T = in_sizes[1] / 64;  // 4096

    char* ws = (char*)d_ws;
    size_t off = 0;
    auto alloc = [&](size_t bytes) {
        char* p = ws + off;
        off += (bytes + 255) & ~(size_t)255;
        return p;
    };
    u16*   xb   = (u16*)alloc((size_t)T * HID * 2);
    u16*   Wqb  = (u16*)alloc((size_t)NQ * HID * 2);   // [2048][1024]
    u16*   Wkb  = (u16*)alloc((size_t)HID * HID * 2);
    u16*   Wvb  = (u16*)alloc((size_t)HID * HID * 2);
    u16*   Wob  = (u16*)alloc((size_t)HID * NQ * 2);   // [1024][2048]
    float* qraw = (float*)alloc((size_t)T * NQ * 4);
    float* kraw = (float*)alloc((size_t)T * HID * 4);
    float* vraw = (float*)alloc((size_t)T * HID * 4);
    u16*   Qb   = (u16*)alloc((size_t)H2 * T * DHEAD * 2);
    u16*   Kb   = (u16*)alloc((size_t)HKV * T * DHEAD * 2);
    u16*   Vbt  = (u16*)alloc((size_t)HKV * DHEAD * T * 2);
    u16*   attn = (u16*)alloc((size_t)T * NQ * 2);

    cast_f32_bf16<<<(T * HID / 4 + 255) / 256, 256, 0, stream>>>(x, xb, T * HID / 4);
    transpose_cast<<<dim3(HID / 32, NQ / 32), 256, 0, stream>>>(Wq, Wqb, HID, NQ);
    transpose_cast<<<dim3(HID / 32, HID / 32), 256, 0, stream>>>(Wk, Wkb, HID, HID);
    transpose_cast<<<dim3(HID / 32, HID / 32), 256, 0, stream>>>(Wv, Wvb, HID, HID);
    transpose_cast<<<dim3(NQ / 32, HID / 32), 256, 0, stream>>>(Wo, Wob, NQ, HID);

    gemm_bf16<<<dim3(NQ / 128, T / 128), 256, 0, stream>>>(xb, Wqb, qraw, T, NQ, HID);
    gemm_bf16<<<dim3(HID / 128, T / 128), 256, 0, stream>>>(xb, Wkb, kraw, T, HID, HID);
    gemm_bf16<<<dim3(HID / 128, T / 128), 256, 0, stream>>>(xb, Wvb, vraw, T, HID, HID);

    const float scale = 0.08838834764831845f;  // 128^-0.5
    norm_rope<<<T * H2 / 4, 256, 0, stream>>>(qraw, cosp, sinp, qnw, Qb, T, H2, scale);
    norm_rope<<<T * HKV / 4, 256, 0, stream>>>(kraw, cosp, sinp, knw, Kb, T, HKV, 1.0f);
    v_transpose<<<dim3(T / 64, HKV), 256, 0, stream>>>(vraw, Vbt, T);

    flash_attn<<<dim3(T / 64, H2), 256, 0, stream>>>(Qb, Kb, Vbt, attn, T);

    gemm_bf16<<<dim3(HID / 128, T / 128), 256, 0, stream>>>(attn, Wob, out, T, HID, NQ);
}